// Round 10
// baseline (471.558 us; speedup 1.0000x reference)
//
#include <hip/hip_runtime.h>
#include <math.h>

// Problem constants
#define NB 2048            // batch
#define ZD 2048            // z dim = 2*512 + 1024, also D_H
#define SD 512             // state dim
#define NELEM_Z (NB * ZD)  // 4194304
#define MB_ (1024 * 1024)

typedef float f32x4 __attribute__((ext_vector_type(4)));
typedef __bf16 bf16x8 __attribute__((ext_vector_type(8)));
typedef __bf16 bf16x4 __attribute__((ext_vector_type(4)));
typedef int i32x4 __attribute__((ext_vector_type(4)));
typedef int i32x8 __attribute__((ext_vector_type(8)));
typedef long long i64;

__device__ __forceinline__ float softplus_f(float x) {
  if (x > 20.f) return x;
  if (x < -20.f) return expf(x);
  return log1pf(expf(x));
}

__device__ __forceinline__ void gload_lds16(const __bf16* g, __bf16* l) {
  __builtin_amdgcn_global_load_lds(
      (__attribute__((address_space(1))) void*)(g),
      (__attribute__((address_space(3))) void*)(l), 16, 0, 0);
}
__device__ __forceinline__ void gload_lds16u(const unsigned char* g,
                                             unsigned char* l) {
  __builtin_amdgcn_global_load_lds(
      (__attribute__((address_space(1))) void*)(g),
      (__attribute__((address_space(3))) void*)(l), 16, 0, 0);
}

// pack 4 floats -> 4 fp8 e4m3 bytes (OCP on gfx950)
__device__ __forceinline__ int pack_fp8x4(float a, float b, float c, float d) {
  int p = __builtin_amdgcn_cvt_pk_fp8_f32(a, b, 0, false);
  p = __builtin_amdgcn_cvt_pk_fp8_f32(c, d, p, true);
  return p;
}
__device__ __forceinline__ float fp8_to_f32(unsigned char b) {
  return __builtin_amdgcn_cvt_f32_fp8((int)b, 0);
}

// ---------------------------------------------------------------------------
// Build z = [q,p,x] (f32/bf16 for q,p only + fp8 full) + VQC encoder angles
// + h_next zero tail (folded).
// ctrl[j] = (j<1024) ? z[1024+j] : z[j-1024]
// ---------------------------------------------------------------------------
__global__ __launch_bounds__(256) void build_z_kernel(
    const float* __restrict__ x,
    const float* __restrict__ h_padded,
    const float* __restrict__ enc_W,  // (2048,6)
    const float* __restrict__ enc_b,  // (6,)
    float* __restrict__ z,
    __bf16* __restrict__ zb,
    unsigned char* __restrict__ zf8,
    float* __restrict__ angles,       // (2048,6)
    float* __restrict__ hnext) {      // (2048,2048) f32: zero tail here
  int b = blockIdx.x;
  int tid = threadIdx.x;
  int lane = tid & 63, w = tid >> 6;
  __shared__ float red[4][6];

  f32x4 zero = {0.f, 0.f, 0.f, 0.f};
  ((f32x4*)hnext)[(size_t)b * 512 + 256 + tid] = zero;

  float pa[6] = {0.f, 0.f, 0.f, 0.f, 0.f, 0.f};
#pragma unroll
  for (int cc = 0; cc < 2; cc++) {
    int c = cc * 256 + tid;  // f32x4 chunk 0..511 within the row
    int i = c * 4;           // element index in z-row
    f32x4 v = (i < 1024) ? ((const f32x4*)(h_padded + (size_t)b * 2048))[c]
                         : ((const f32x4*)(x + (size_t)b * 1024))[c - 256];
    size_t zi = (size_t)b * 512 + c;
    if (cc == 0) {  // q,p half: keep f32 + bf16 mirrors
      ((f32x4*)z)[zi] = v;
      bf16x4 o;
      o[0] = (__bf16)v[0]; o[1] = (__bf16)v[1];
      o[2] = (__bf16)v[2]; o[3] = (__bf16)v[3];
      ((bf16x4*)zb)[zi] = o;
    }
    ((int*)zf8)[zi] = pack_fp8x4(v[0], v[1], v[2], v[3]);
    int cj = (i < 1024) ? (1024 + i) : (i - 1024);  // ctrl index of v[0]
#pragma unroll
    for (int e = 0; e < 4; e++) {
      const float* wp = enc_W + (size_t)(cj + e) * 6;
#pragma unroll
      for (int k = 0; k < 6; k++) pa[k] += v[e] * wp[k];
    }
  }
#pragma unroll
  for (int k = 0; k < 6; k++)
    for (int off = 32; off > 0; off >>= 1) pa[k] += __shfl_down(pa[k], off, 64);
  if (lane == 0) {
#pragma unroll
    for (int k = 0; k < 6; k++) red[w][k] = pa[k];
  }
  __syncthreads();
  if (tid < 6)
    angles[b * 6 + tid] =
        red[0][tid] + red[1][tid] + red[2][tid] + red[3][tid] + enc_b[tid];
}

// ---------------------------------------------------------------------------
// All weight prep in ONE launch, grid (64,64,3).
// ---------------------------------------------------------------------------
__global__ void prep_all(const float* __restrict__ W1,
                         const float* __restrict__ W2,
                         const float* __restrict__ Wout,
                         unsigned char* __restrict__ N1,
                         unsigned char* __restrict__ T1,
                         unsigned char* __restrict__ N2,
                         unsigned char* __restrict__ T2,
                         __bf16* __restrict__ WoT) {
  __shared__ float tile[32][33];
  int bx = blockIdx.x * 32, by = blockIdx.y * 32;
  int tx = threadIdx.x, ty = threadIdx.y;

  if (blockIdx.z == 2) {
    if (blockIdx.x >= 32 || blockIdx.y >= 32) return;
    for (int r = ty; r < 32; r += 8)
      tile[r][tx] = Wout[(size_t)(by + r) * 1024 + bx + tx];
    __syncthreads();
    for (int r = ty; r < 32; r += 8)
      WoT[(size_t)(bx + r) * 1024 + by + tx] = (__bf16)tile[tx][r];
    return;
  }

  const float* in = blockIdx.z ? W2 : W1;
  unsigned char* outN = blockIdx.z ? N2 : N1;
  unsigned char* outT = blockIdx.z ? T2 : T1;
  for (int r = ty; r < 32; r += 8) {
    float v = in[(size_t)(by + r) * ZD + bx + tx] * 16.f;
    tile[r][tx] = v;
    int p = __builtin_amdgcn_cvt_pk_fp8_f32(v, v, 0, false);
    outN[(size_t)(by + r) * ZD + bx + tx] = (unsigned char)(p & 0xff);
  }
  __syncthreads();
  for (int r = ty; r < 32; r += 8) {
    float v = tile[tx][r];
    int p = __builtin_amdgcn_cvt_pk_fp8_f32(v, v, 0, false);
    outT[(size_t)(bx + r) * ZD + by + tx] = (unsigned char)(p & 0xff);
  }
}

// ---------------------------------------------------------------------------
// Statevector sim v3: one batch row per WAVE; lane i holds amplitude i.
// ---------------------------------------------------------------------------
__global__ __launch_bounds__(256) void sim_kernel(
    const float* __restrict__ angles,  // (2048,6)
    const float* __restrict__ thetas,  // (3,6)
    const float* __restrict__ gain,
    const float* __restrict__ shift,
    float* __restrict__ partial) {     // (512,)
  const int lane = threadIdx.x & 63;
  const int wv = threadIdx.x >> 6;
  const int row = blockIdx.x * 4 + wv;

  const int rot = ((lane << 1) | (lane >> 5)) & 63;
  const float czs = (__popc(lane & rot) & 1) ? -1.f : 1.f;
  const float zo = (6.f - 2.f * (float)__popc(lane)) * (1.f / 6.f);

  float ang = 0.f;
  if (lane < 6) ang = angles[row * 6 + lane];
  else if (lane < 24) ang = thetas[lane - 6];
  float half = 0.5f * ang;
  float cj = cosf(half), sj = sinf(half);

  float c_arr[24], s_arr[24];
#pragma unroll
  for (int j = 0; j < 24; j++) {
    c_arr[j] = __shfl(cj, j, 64);
    s_arr[j] = __shfl(sj, j, 64);
  }

  float s = (lane == 0) ? 1.f : 0.f;
#pragma unroll
  for (int j = 0; j < 24; j++) {
    const int m = 1 << (5 - (j % 6));
    float t = __shfl_xor(s, m, 64);
    float tt = (lane & m) ? t : -t;
    s = fmaf(c_arr[j], s, s_arr[j] * tt);
    if (j >= 6 && (j % 6) == 5) s *= czs;  // CZ ring after each VQC layer
  }

  float val = s * s * zo;
#pragma unroll
  for (int off = 32; off > 0; off >>= 1) val += __shfl_xor(val, off, 64);

  __shared__ float red[4];
  if (lane == 0) {
    float sg = softplus_f(gain[0]);
    float ss = softplus_f(shift[0]);
    red[wv] = softplus_f(sg * val - ss);
  }
  __syncthreads();
  if (threadIdx.x == 0)
    partial[blockIdx.x] = red[0] + red[1] + red[2] + red[3];
}

// ---------------------------------------------------------------------------
// dt: reduce 512 block-partials (one 256-thr block) + scalar chain
// ---------------------------------------------------------------------------
__global__ __launch_bounds__(256) void dt_kernel(
    const float* __restrict__ partial,
    const float* __restrict__ cap_param,
    const float* __restrict__ time_bias,
    const float* __restrict__ last_stable,
    float* __restrict__ dt_out) {
  int tid = threadIdx.x;
  int lane = tid & 63, wv = tid >> 6;
  float v = partial[tid] + partial[tid + 256];
#pragma unroll
  for (int off = 32; off > 0; off >>= 1) v += __shfl_xor(v, off, 64);
  __shared__ float red[4];
  if (lane == 0) red[wv] = v;
  __syncthreads();
  if (tid == 0) {
    float a = red[0] + red[1] + red[2] + red[3];
    float raw = a * (1.f / (float)NB) + time_bias[0];
    float cap = fmaxf(softplus_f(cap_param[0]), 1e-6f);
    float evo = cap / (1.f + expf(-raw / cap));
    if (!isfinite(evo)) evo = cap / (1.f + expf(-time_bias[0] / cap));
    float prev = fmaxf(last_stable[0], 1e-6f);
    float cand = fmaxf(evo, 1e-6f);
    float max_step = fmaxf(prev * 0.1f, 1e-4f);
    cand = fminf(cand, prev + max_step);
    cand = fminf(cand, 0.05f);
    dt_out[0] = isfinite(cand) ? cand : prev;
  }
}

// ---------------------------------------------------------------------------
// fp8 MX-MFMA GEMM v8: OCCUPANCY build. r9 PMC: MfmaUtil 7%, VALU 15%,
// HBM 5%, Occ 19.5% — nothing saturated, and 4 different inner loops all
// neutral => latency-bound at 8 waves/CU (2/SIMD, lockstep). v8 shrinks the
// tile to 64x64 (wave-tile 32x32, 4 waves): 3-buf LDS = 48 KiB -> 3 blk/CU,
// grid 32x32 = 1024 blocks -> 12 waves/CU, 3 independent block-streams
// (+50% TLP; +33% LDS/L2 traffic accepted — nothing was saturated).
// Pipeline: r8's 2-tile-deep counted vmcnt (per wave 4 loads/tile; wait
// vmcnt(4) keeps next tile's 4 in flight across the barrier).
// XCD swizzle (square, gridDim.x==32): each XCD gets an 8x16-tile region
// (A 16x64 rows=2MB + B 8x64 cols=1MB = 3MB < 4MB L2).
// Per-output accumulation order unchanged -> bit-identical results.
// EPI: 0 f32 partial (split-K) | 1 fp8 tanh(v/16+bias)
//      2 fp8 32*(1-t^2)*w3[col] | 3 fp8 (v/16)*(1-h^2)
// ---------------------------------------------------------------------------
template <int EPI>
__global__ __launch_bounds__(256, 3) void mfma_gemm8(
    const unsigned char* __restrict__ A, int lda,
    const unsigned char* __restrict__ Bt, int ldb,
    void* __restrict__ Cv, int ldc,
    const float* __restrict__ bias,
    const float* __restrict__ w3,
    const unsigned char* __restrict__ aux, int ldaux,
    int Kslice) {
  __shared__ __align__(16) unsigned char sA[3][64 * 128];
  __shared__ __align__(16) unsigned char sB[3][64 * 128];

  const int tid = threadIdx.x;
  const int lane = tid & 63;
  const int w = tid >> 6;
  const int wm = w & 1, wn = w >> 1;   // 2x2 waves, wave-tile 32x32

  int bx = blockIdx.x, by = blockIdx.y;
  if (gridDim.x == 32 && gridDim.y == 32) {  // square: XCD 8x16 region remap
    int bid = by * 32 + bx;
    int xcd = bid & 7, k = bid >> 3;   // k in 0..127
    bx = (xcd & 3) * 8 + (k & 7);
    by = (xcd >> 2) * 16 + (k >> 3);
  }
  const int row0 = by * 64;
  const int col0 = bx * 64;
  const int koff = blockIdx.z * Kslice;

  // staging: linear LDS dest c*16, pre-swizzled global source.
  const unsigned char* gA[2]; int dA[2];
  const unsigned char* gB[2]; int dB[2];
#pragma unroll
  for (int i = 0; i < 2; i++) {
    int c = i * 256 + tid;       // 0..511
    int m = c >> 3, s = c & 7;   // row, phys 16B slot
    int l = s ^ (m & 7);         // logical slot feeding phys s
    gA[i] = A + (size_t)(row0 + m) * lda + koff + l * 16;
    gB[i] = Bt + (size_t)(col0 + m) * ldb + koff + l * 16;
    dA[i] = c * 16;
    dB[i] = c * 16;
  }

  // fragment read offsets: logical slots 2q,2q+1, phys XOR'd by (row&7)
  const int q = lane >> 4, r = lane & 15;
  int aoff[2][2], boff[2][2];
#pragma unroll
  for (int i = 0; i < 2; i++) {
    int ma = wm * 32 + i * 16 + r;
#pragma unroll
    for (int H = 0; H < 2; H++)
      aoff[i][H] = ma * 128 + (((2 * q + H) ^ (ma & 7)) << 4);
  }
#pragma unroll
  for (int j = 0; j < 2; j++) {
    int mb = wn * 32 + j * 16 + r;
#pragma unroll
    for (int H = 0; H < 2; H++)
      boff[j][H] = mb * 128 + (((2 * q + H) ^ (mb & 7)) << 4);
  }

  f32x4 acc[2][2] = {};

  auto issue = [&](int k0, int bi) {
#pragma unroll
    for (int i = 0; i < 2; i++)
      gload_lds16u(gA[i] + k0, &sA[bi][0] + dA[i]);
#pragma unroll
    for (int i = 0; i < 2; i++)
      gload_lds16u(gB[i] + k0, &sB[bi][0] + dB[i]);
  };
  auto compute = [&](int bi) {
    const unsigned char* bA = &sA[bi][0];
    const unsigned char* bB = &sB[bi][0];
    i32x8 af[2], bfr[2];
#pragma unroll
    for (int i = 0; i < 2; i++) {
      i32x4 lo = *(const i32x4*)(bA + aoff[i][0]);
      i32x4 hi = *(const i32x4*)(bA + aoff[i][1]);
      af[i] = __builtin_shufflevector(lo, hi, 0, 1, 2, 3, 4, 5, 6, 7);
    }
#pragma unroll
    for (int j = 0; j < 2; j++) {
      i32x4 lo = *(const i32x4*)(bB + boff[j][0]);
      i32x4 hi = *(const i32x4*)(bB + boff[j][1]);
      bfr[j] = __builtin_shufflevector(lo, hi, 0, 1, 2, 3, 4, 5, 6, 7);
    }
    __builtin_amdgcn_s_setprio(1);
#pragma unroll
    for (int i = 0; i < 2; i++)
#pragma unroll
      for (int j = 0; j < 2; j++)
        acc[i][j] = __builtin_amdgcn_mfma_scale_f32_16x16x128_f8f6f4(
            af[i], bfr[j], acc[i][j], 0 /*fp8 A*/, 0 /*fp8 B*/,
            0, 0x7F7F7F7F, 0, 0x7F7F7F7F);  // unit scales
    __builtin_amdgcn_s_setprio(0);
  };

  const int nt = Kslice >> 7;  // 16 square / 4 grad, always >= 2

  // prologue: 2 tiles in flight (4 loads each)
  issue(0, 0);
  issue(128, 1);

  for (int t = 0; t < nt - 1; ++t) {
    asm volatile("s_waitcnt vmcnt(4)" ::: "memory");  // tile t landed
    __builtin_amdgcn_s_barrier();
    __builtin_amdgcn_sched_barrier(0);
    if (t + 2 < nt) issue((t + 2) << 7, (t + 2) % 3);
    compute(t % 3);
  }
  asm volatile("s_waitcnt vmcnt(0)" ::: "memory");
  __builtin_amdgcn_s_barrier();
  __builtin_amdgcn_sched_barrier(0);
  compute((nt - 1) % 3);

  // epilogue: C/D layout col=lane&15, row=(lane>>4)*4+reg
  float* Cf = (float*)Cv;
  unsigned char* C8 = (unsigned char*)Cv;
  float* Pz = Cf + (size_t)blockIdx.z * (size_t)gridDim.y * 64 * ldc;

#pragma unroll
  for (int i = 0; i < 2; i++) {
    int rowb = row0 + wm * 32 + i * 16 + q * 4;
#pragma unroll
    for (int j = 0; j < 2; j++) {
      int col = col0 + wn * 32 + j * 16 + r;
      if (EPI == 0) {
#pragma unroll
        for (int g = 0; g < 4; g++)
          Pz[(size_t)(rowb + g) * ldc + col] = acc[i][j][g];
      } else {
        float o[4];
#pragma unroll
        for (int g = 0; g < 4; g++) {
          float v = acc[i][j][g] * 0.0625f;  // undo weight x16
          if (EPI == 1) {
            o[g] = tanhf(v + bias[col]);
          } else if (EPI == 2) {
            float t = tanhf(v + bias[col]);
            o[g] = 32.f * (1.f - t * t) * w3[col];
          } else {
            float h = fp8_to_f32(aux[(size_t)(rowb + g) * ldaux + col]);
            o[g] = v * (1.f - h * h);
          }
        }
        int p = pack_fp8x4(o[0], o[1], o[2], o[3]);
#pragma unroll
        for (int g = 0; g < 4; g++)
          C8[(size_t)(rowb + g) * ldc + col] =
              (unsigned char)((p >> (8 * g)) & 0xff);
      }
    }
  }
}

// ---------------------------------------------------------------------------
// bf16 MFMA GEMM (W_out only, precision-critical): f32 split-K partials.
// ---------------------------------------------------------------------------
__global__ __launch_bounds__(256, 2) void mfma_gemm_bf16(
    const __bf16* __restrict__ A, int lda,
    const __bf16* __restrict__ Bt, int ldb,
    float* __restrict__ P, int ldc,
    int Kslice) {
  __shared__ __bf16 sA[2][128 * 64];
  __shared__ __bf16 sB[2][64 * 64];

  const int tid = threadIdx.x;
  const int lane = tid & 63;
  const int w = tid >> 6;
  const int wm = w & 1, wn = w >> 1;
  const int row0 = blockIdx.y * 128;
  const int col0 = blockIdx.x * 64;
  const int koff = blockIdx.z * Kslice;

  const __bf16* gA[4]; int lofA[4];
  const __bf16* gB[2]; int lofB[2];
#pragma unroll
  for (int i = 0; i < 4; i++) {
    int c = i * 256 + tid;
    int m = c >> 3, cc = c & 7;
    int o = cc ^ (m & 7);
    gA[i] = A + (size_t)(row0 + m) * lda + koff + o * 8;
    lofA[i] = c * 8;
  }
#pragma unroll
  for (int i = 0; i < 2; i++) {
    int c = i * 256 + tid;
    int m = c >> 3, cc = c & 7;
    int o = cc ^ (m & 7);
    gB[i] = Bt + (size_t)(col0 + m) * ldb + koff + o * 8;
    lofB[i] = c * 8;
  }

  const int q = lane >> 4, r = lane & 15;
  int aoff[4][2], boff[2][2];
#pragma unroll
  for (int i = 0; i < 4; i++) {
    int ma = wm * 64 + i * 16 + r;
#pragma unroll
    for (int h = 0; h < 2; h++)
      aoff[i][h] = (ma * 8 + ((h * 4 + q) ^ (ma & 7))) * 8;
  }
#pragma unroll
  for (int j = 0; j < 2; j++) {
    int mb = wn * 32 + j * 16 + r;
#pragma unroll
    for (int h = 0; h < 2; h++)
      boff[j][h] = (mb * 8 + ((h * 4 + q) ^ (mb & 7))) * 8;
  }

  f32x4 acc[4][2] = {};

#pragma unroll
  for (int i = 0; i < 4; i++) gload_lds16(gA[i], &sA[0][0] + lofA[i]);
#pragma unroll
  for (int i = 0; i < 2; i++) gload_lds16(gB[i], &sB[0][0] + lofB[i]);

  int cur = 0;
  for (int k0 = 0; k0 < Kslice; k0 += 64) {
    __syncthreads();
    if (k0 + 64 < Kslice) {
      int nxt = cur ^ 1;
#pragma unroll
      for (int i = 0; i < 4; i++)
        gload_lds16(gA[i] + k0 + 64, &sA[nxt][0] + lofA[i]);
#pragma unroll
      for (int i = 0; i < 2; i++)
        gload_lds16(gB[i] + k0 + 64, &sB[nxt][0] + lofB[i]);
    }
#pragma unroll
    for (int h = 0; h < 2; h++) {
      bf16x8 af[4], bfr[2];
#pragma unroll
      for (int i = 0; i < 4; i++)
        af[i] = *(const bf16x8*)(&sA[cur][0] + aoff[i][h]);
#pragma unroll
      for (int j = 0; j < 2; j++)
        bfr[j] = *(const bf16x8*)(&sB[cur][0] + boff[j][h]);
#pragma unroll
      for (int i = 0; i < 4; i++)
#pragma unroll
        for (int j = 0; j < 2; j++)
          acc[i][j] = __builtin_amdgcn_mfma_f32_16x16x32_bf16(af[i], bfr[j],
                                                              acc[i][j], 0, 0, 0);
    }
    cur ^= 1;
  }

  float* Pz = P + (size_t)blockIdx.z * (size_t)gridDim.y * 128 * ldc;
#pragma unroll
  for (int i = 0; i < 4; i++) {
    int rowb = row0 + wm * 64 + i * 16 + q * 4;
#pragma unroll
    for (int j = 0; j < 2; j++) {
      int col = col0 + wn * 32 + j * 16 + r;
#pragma unroll
      for (int g = 0; g < 4; g++)
        Pz[(size_t)(rowb + g) * ldc + col] = acc[i][j][g];
    }
  }
}

// ---------------------------------------------------------------------------
// grad = sum of 4 split-K partials (scaled 1/512 for fp8 scales);
// z[:, off:off+512] += coef*dt*grad ; refresh zb (bf16) and zf8 (fp8).
// If hout != nullptr (final q/p updates), also write into out_hnxt.
// ---------------------------------------------------------------------------
__global__ void update_kernel(float* __restrict__ z, __bf16* __restrict__ zb,
                              unsigned char* __restrict__ zf8,
                              const float* __restrict__ gp,
                              const float* __restrict__ dt,
                              float coef, int off,
                              float* __restrict__ hout) {
  int t = blockIdx.x * blockDim.x + threadIdx.x;  // 0 .. NB*SD/4
  int b = t >> 7;
  int j4 = t & 127;
  const f32x4* g4 = (const f32x4*)gp;
  constexpr int STRIDE = NB * SD / 4;
  f32x4 g = g4[t] + g4[t + STRIDE] + g4[t + 2 * STRIDE] + g4[t + 3 * STRIDE];
  int zi4 = (b * ZD + off) / 4 + j4;
  f32x4 v = ((f32x4*)z)[zi4];
  float s = coef * dt[0] * (1.f / 512.f);  // undo x16(w) * x32(g1)
  v[0] += s * g[0]; v[1] += s * g[1]; v[2] += s * g[2]; v[3] += s * g[3];
  ((f32x4*)z)[zi4] = v;
  bf16x4 o;
  o[0] = (__bf16)v[0]; o[1] = (__bf16)v[1];
  o[2] = (__bf16)v[2]; o[3] = (__bf16)v[3];
  ((bf16x4*)zb)[zi4] = o;
  ((int*)zf8)[zi4] = pack_fp8x4(v[0], v[1], v[2], v[3]);
  if (hout) {  // h_next row stride 2048 f32 = 512 f32x4; [q,p] = first 1024
    ((f32x4*)hout)[b * 512 + (off >> 2) + j4] = v;
  }
}

// ---------------------------------------------------------------------------
// W_out split-K=2 reduce + bias (f32, x4 vec)
// ---------------------------------------------------------------------------
__global__ void wout_reduce(const float* __restrict__ gp,
                            const float* __restrict__ b_out,
                            float* __restrict__ out) {
  int t = blockIdx.x * blockDim.x + threadIdx.x;  // 0 .. NB*1024/4
  constexpr int S = NB * 1024 / 4;
  const f32x4* g4 = (const f32x4*)gp;
  f32x4 v = g4[t] + g4[t + S];
  f32x4 bb = ((const f32x4*)b_out)[t & 255];
  v[0] += bb[0]; v[1] += bb[1]; v[2] += bb[2]; v[3] += bb[3];
  ((f32x4*)out)[t] = v;
}

// ---------------------------------------------------------------------------
extern "C" void kernel_launch(void* const* d_in, const int* in_sizes, int n_in,
                              void* d_out, int out_size, void* d_ws,
                              size_t ws_size, hipStream_t stream) {
  const float* x        = (const float*)d_in[0];
  const float* h_padded = (const float*)d_in[1];
  const float* W1    = (const float*)d_in[3];
  const float* b1    = (const float*)d_in[4];
  const float* W2    = (const float*)d_in[5];
  const float* b2    = (const float*)d_in[6];
  const float* W3    = (const float*)d_in[7];
  const float* W_out = (const float*)d_in[9];
  const float* b_out = (const float*)d_in[10];
  const float* enc_W = (const float*)d_in[11];
  const float* enc_b = (const float*)d_in[12];
  const float* thetas = (const float*)d_in[13];
  const float* gain   = (const float*)d_in[14];
  const float* shift  = (const float*)d_in[15];
  const float* cap_p  = (const float*)d_in[16];
  const float* t_bias = (const float*)d_in[17];
  const float* l_stab = (const float*)d_in[18];

  float* out_mat  = (float*)d_out;              // (2048,1024)
  float* out_hnxt = (float*)d_out + NB * 1024;  // (2048,16,128)

  // workspace layout (bytes)
  char* base = (char*)d_ws;
  float* z      = (float*)(base);                      // 16MB f32
  float* part   = (float*)(base + 16 * MB_);           // 16MB f32 partials
  __bf16* zb    = (__bf16*)(base + 32 * MB_);          // 8MB bf16
  __bf16* Wot   = (__bf16*)(base + 40 * MB_);          // 2MB bf16
  float* angl   = (float*)(base + 42 * MB_);           // 48KB
  float* dtp    = (float*)(base + 42 * MB_ + 65536);   // scalar
  float* simp   = (float*)(base + 42 * MB_ + 80 * 1024);  // 512 partials
  unsigned char* zf8  = (unsigned char*)(base + 43 * MB_);  // 4MB each:
  unsigned char* h1_8 = zf8 + (size_t)NELEM_Z;
  unsigned char* g2_8 = h1_8 + (size_t)NELEM_Z;
  unsigned char* g1_8 = g2_8 + (size_t)NELEM_Z;
  unsigned char* W1n8 = g1_8 + (size_t)NELEM_Z;
  unsigned char* W1t8 = W1n8 + (size_t)NELEM_Z;
  unsigned char* W2n8 = W1t8 + (size_t)NELEM_Z;
  unsigned char* W2t8 = W2n8 + (size_t)NELEM_Z;

  dim3 thr256(256);
  dim3 thrT(32, 8);

  // 1. weight prep: single launch (W1, W2 fp8 x16; W_out bf16^T)
  prep_all<<<dim3(64, 64, 3), thrT, 0, stream>>>(W1, W2, W_out, W1n8, W1t8,
                                                 W2n8, W2t8, Wot);

  // 2. build z (f32/bf16/fp8) + angles + h_next zero tail; then sim + dt
  build_z_kernel<<<dim3(NB), thr256, 0, stream>>>(x, h_padded, enc_W, enc_b, z,
                                                  zb, zf8, angl, out_hnxt);
  sim_kernel<<<dim3(NB / 4), thr256, 0, stream>>>(angl, thetas, gain, shift,
                                                  simp);
  dt_kernel<<<dim3(1), thr256, 0, stream>>>(simp, cap_p, t_bias, l_stab, dtp);

  // 3. three leapfrog gradient evaluations (all-fp8 MX grad path)
  const int   j0r[3]  = {0, 512, 0};
  const int   offs[3] = {512, 0, 512};
  const float coef[3] = {-0.5f, 1.0f, -0.5f};
  float* houts[3];
  houts[0] = nullptr;    // p_half: internal only
  houts[1] = out_hnxt;   // q_next -> h_next[:, 0:512]
  houts[2] = out_hnxt;   // p_next -> h_next[:, 512:1024]

  dim3 gridSq(32, 32, 1);   // 2048x2048, 64x64 tiles -> 1024 blocks (3/CU res)
  dim3 gridGr(8, 32, 4);    // 2048x512, split-K=4    -> 1024 blocks

  for (int i = 0; i < 3; i++) {
    // h1 = tanh(z @ W1 + b1)                       (fp8 out)
    mfma_gemm8<1><<<gridSq, thr256, 0, stream>>>(
        zf8, ZD, W1t8, ZD, h1_8, ZD, b1, nullptr, nullptr, 0, ZD);
    // g2 = 32*(1 - tanh(h1 @ W2 + b2)^2) * W3[col] (fp8 out)
    mfma_gemm8<2><<<gridSq, thr256, 0, stream>>>(
        h1_8, ZD, W2t8, ZD, g2_8, ZD, b2, W3, nullptr, 0, ZD);
    // g1 = (g2 @ W2^T)/16 * (1 - h1^2)             (fp8 out, carries x32)
    mfma_gemm8<3><<<gridSq, thr256, 0, stream>>>(
        g2_8, ZD, W2n8, ZD, g1_8, ZD, nullptr, nullptr, h1_8, ZD, ZD);
    // part = g1 @ W1[j0:j0+512,:]^T  (f32 partials, split-K=4)
    mfma_gemm8<0><<<gridGr, thr256, 0, stream>>>(
        g1_8, ZD, W1n8 + (size_t)j0r[i] * ZD, ZD, part, SD, nullptr, nullptr,
        nullptr, 0, 512);
    // z[:, offs] += coef*dt*sum(part)/512  (+ h_next write on i=1,2)
    update_kernel<<<dim3(NB * SD / 4 / 256), thr256, 0, stream>>>(
        z, zb, zf8, part, dtp, coef[i], offs[i], houts[i]);
  }

  // 4. out = z[:, :1024] @ W_out + b_out  (bf16, split-K=2 + reduce)
  mfma_gemm_bf16<<<dim3(16, 16, 2), thr256, 0, stream>>>(zb, ZD, Wot, 1024,
                                                         part, 1024, 512);
  wout_reduce<<<dim3(NB * 1024 / 4 / 256), thr256, 0, stream>>>(part, b_out,
                                                                out_mat);
}

// Round 11
// 402.904 us; speedup vs baseline: 1.1704x; 1.1704x over previous
//
#include <hip/hip_runtime.h>
#include <math.h>

// Problem constants
#define NB 2048            // batch
#define ZD 2048            // z dim = 2*512 + 1024, also D_H
#define SD 512             // state dim
#define NELEM_Z (NB * ZD)  // 4194304
#define MB_ (1024 * 1024)

typedef float f32x4 __attribute__((ext_vector_type(4)));
typedef __bf16 bf16x8 __attribute__((ext_vector_type(8)));
typedef __bf16 bf16x4 __attribute__((ext_vector_type(4)));
typedef int i32x4 __attribute__((ext_vector_type(4)));
typedef int i32x8 __attribute__((ext_vector_type(8)));
typedef long long i64;

__device__ __forceinline__ float softplus_f(float x) {
  if (x > 20.f) return x;
  if (x < -20.f) return expf(x);
  return log1pf(expf(x));
}

__device__ __forceinline__ void gload_lds16(const __bf16* g, __bf16* l) {
  __builtin_amdgcn_global_load_lds(
      (__attribute__((address_space(1))) void*)(g),
      (__attribute__((address_space(3))) void*)(l), 16, 0, 0);
}

// pack 4 floats -> 4 fp8 e4m3 bytes (OCP on gfx950)
__device__ __forceinline__ int pack_fp8x4(float a, float b, float c, float d) {
  int p = __builtin_amdgcn_cvt_pk_fp8_f32(a, b, 0, false);
  p = __builtin_amdgcn_cvt_pk_fp8_f32(c, d, p, true);
  return p;
}
__device__ __forceinline__ float fp8_to_f32(unsigned char b) {
  return __builtin_amdgcn_cvt_f32_fp8((int)b, 0);
}

// ---------------------------------------------------------------------------
// Build z = [q,p,x] (f32/bf16 for q,p only + fp8 full) + VQC encoder angles
// + h_next zero tail (folded).
// ctrl[j] = (j<1024) ? z[1024+j] : z[j-1024]
// ---------------------------------------------------------------------------
__global__ __launch_bounds__(256) void build_z_kernel(
    const float* __restrict__ x,
    const float* __restrict__ h_padded,
    const float* __restrict__ enc_W,  // (2048,6)
    const float* __restrict__ enc_b,  // (6,)
    float* __restrict__ z,
    __bf16* __restrict__ zb,
    unsigned char* __restrict__ zf8,
    float* __restrict__ angles,       // (2048,6)
    float* __restrict__ hnext) {      // (2048,2048) f32: zero tail here
  int b = blockIdx.x;
  int tid = threadIdx.x;
  int lane = tid & 63, w = tid >> 6;
  __shared__ float red[4][6];

  f32x4 zero = {0.f, 0.f, 0.f, 0.f};
  ((f32x4*)hnext)[(size_t)b * 512 + 256 + tid] = zero;

  float pa[6] = {0.f, 0.f, 0.f, 0.f, 0.f, 0.f};
#pragma unroll
  for (int cc = 0; cc < 2; cc++) {
    int c = cc * 256 + tid;  // f32x4 chunk 0..511 within the row
    int i = c * 4;           // element index in z-row
    f32x4 v = (i < 1024) ? ((const f32x4*)(h_padded + (size_t)b * 2048))[c]
                         : ((const f32x4*)(x + (size_t)b * 1024))[c - 256];
    size_t zi = (size_t)b * 512 + c;
    if (cc == 0) {  // q,p half: keep f32 + bf16 mirrors
      ((f32x4*)z)[zi] = v;
      bf16x4 o;
      o[0] = (__bf16)v[0]; o[1] = (__bf16)v[1];
      o[2] = (__bf16)v[2]; o[3] = (__bf16)v[3];
      ((bf16x4*)zb)[zi] = o;
    }
    ((int*)zf8)[zi] = pack_fp8x4(v[0], v[1], v[2], v[3]);
    int cj = (i < 1024) ? (1024 + i) : (i - 1024);  // ctrl index of v[0]
#pragma unroll
    for (int e = 0; e < 4; e++) {
      const float* wp = enc_W + (size_t)(cj + e) * 6;
#pragma unroll
      for (int k = 0; k < 6; k++) pa[k] += v[e] * wp[k];
    }
  }
#pragma unroll
  for (int k = 0; k < 6; k++)
    for (int off = 32; off > 0; off >>= 1) pa[k] += __shfl_down(pa[k], off, 64);
  if (lane == 0) {
#pragma unroll
    for (int k = 0; k < 6; k++) red[w][k] = pa[k];
  }
  __syncthreads();
  if (tid < 6)
    angles[b * 6 + tid] =
        red[0][tid] + red[1][tid] + red[2][tid] + red[3][tid] + enc_b[tid];
}

// ---------------------------------------------------------------------------
// All weight prep in ONE launch, grid (64,64,3):
//  z=0: W1 -> fp8 straight+transposed (x16); z=1: W2 same;
//  z=2 (blocks <32x32 only): W_out f32 -> transposed bf16.
// ---------------------------------------------------------------------------
__global__ void prep_all(const float* __restrict__ W1,
                         const float* __restrict__ W2,
                         const float* __restrict__ Wout,
                         unsigned char* __restrict__ N1,
                         unsigned char* __restrict__ T1,
                         unsigned char* __restrict__ N2,
                         unsigned char* __restrict__ T2,
                         __bf16* __restrict__ WoT) {
  __shared__ float tile[32][33];
  int bx = blockIdx.x * 32, by = blockIdx.y * 32;
  int tx = threadIdx.x, ty = threadIdx.y;

  if (blockIdx.z == 2) {
    if (blockIdx.x >= 32 || blockIdx.y >= 32) return;
    for (int r = ty; r < 32; r += 8)
      tile[r][tx] = Wout[(size_t)(by + r) * 1024 + bx + tx];
    __syncthreads();
    for (int r = ty; r < 32; r += 8)
      WoT[(size_t)(bx + r) * 1024 + by + tx] = (__bf16)tile[tx][r];
    return;
  }

  const float* in = blockIdx.z ? W2 : W1;
  unsigned char* outN = blockIdx.z ? N2 : N1;
  unsigned char* outT = blockIdx.z ? T2 : T1;
  for (int r = ty; r < 32; r += 8) {
    float v = in[(size_t)(by + r) * ZD + bx + tx] * 16.f;
    tile[r][tx] = v;
    int p = __builtin_amdgcn_cvt_pk_fp8_f32(v, v, 0, false);
    outN[(size_t)(by + r) * ZD + bx + tx] = (unsigned char)(p & 0xff);
  }
  __syncthreads();
  for (int r = ty; r < 32; r += 8) {
    float v = tile[tx][r];
    int p = __builtin_amdgcn_cvt_pk_fp8_f32(v, v, 0, false);
    outT[(size_t)(bx + r) * ZD + by + tx] = (unsigned char)(p & 0xff);
  }
}

// ---------------------------------------------------------------------------
// Statevector sim v3: one batch row per WAVE; lane i holds amplitude i.
// ---------------------------------------------------------------------------
__global__ __launch_bounds__(256) void sim_kernel(
    const float* __restrict__ angles,  // (2048,6)
    const float* __restrict__ thetas,  // (3,6)
    const float* __restrict__ gain,
    const float* __restrict__ shift,
    float* __restrict__ partial) {     // (512,)
  const int lane = threadIdx.x & 63;
  const int wv = threadIdx.x >> 6;
  const int row = blockIdx.x * 4 + wv;

  const int rot = ((lane << 1) | (lane >> 5)) & 63;
  const float czs = (__popc(lane & rot) & 1) ? -1.f : 1.f;
  const float zo = (6.f - 2.f * (float)__popc(lane)) * (1.f / 6.f);

  float ang = 0.f;
  if (lane < 6) ang = angles[row * 6 + lane];
  else if (lane < 24) ang = thetas[lane - 6];
  float half = 0.5f * ang;
  float cj = cosf(half), sj = sinf(half);

  float c_arr[24], s_arr[24];
#pragma unroll
  for (int j = 0; j < 24; j++) {
    c_arr[j] = __shfl(cj, j, 64);
    s_arr[j] = __shfl(sj, j, 64);
  }

  float s = (lane == 0) ? 1.f : 0.f;
#pragma unroll
  for (int j = 0; j < 24; j++) {
    const int m = 1 << (5 - (j % 6));
    float t = __shfl_xor(s, m, 64);
    float tt = (lane & m) ? t : -t;
    s = fmaf(c_arr[j], s, s_arr[j] * tt);
    if (j >= 6 && (j % 6) == 5) s *= czs;  // CZ ring after each VQC layer
  }

  float val = s * s * zo;
#pragma unroll
  for (int off = 32; off > 0; off >>= 1) val += __shfl_xor(val, off, 64);

  __shared__ float red[4];
  if (lane == 0) {
    float sg = softplus_f(gain[0]);
    float ss = softplus_f(shift[0]);
    red[wv] = softplus_f(sg * val - ss);
  }
  __syncthreads();
  if (threadIdx.x == 0)
    partial[blockIdx.x] = red[0] + red[1] + red[2] + red[3];
}

// ---------------------------------------------------------------------------
// dt: reduce 512 block-partials (one 256-thr block) + scalar chain
// ---------------------------------------------------------------------------
__global__ __launch_bounds__(256) void dt_kernel(
    const float* __restrict__ partial,
    const float* __restrict__ cap_param,
    const float* __restrict__ time_bias,
    const float* __restrict__ last_stable,
    float* __restrict__ dt_out) {
  int tid = threadIdx.x;
  int lane = tid & 63, wv = tid >> 6;
  float v = partial[tid] + partial[tid + 256];
#pragma unroll
  for (int off = 32; off > 0; off >>= 1) v += __shfl_xor(v, off, 64);
  __shared__ float red[4];
  if (lane == 0) red[wv] = v;
  __syncthreads();
  if (tid == 0) {
    float a = red[0] + red[1] + red[2] + red[3];
    float raw = a * (1.f / (float)NB) + time_bias[0];
    float cap = fmaxf(softplus_f(cap_param[0]), 1e-6f);
    float evo = cap / (1.f + expf(-raw / cap));
    if (!isfinite(evo)) evo = cap / (1.f + expf(-time_bias[0] / cap));
    float prev = fmaxf(last_stable[0], 1e-6f);
    float cand = fmaxf(evo, 1e-6f);
    float max_step = fmaxf(prev * 0.1f, 1e-4f);
    cand = fminf(cand, prev + max_step);
    cand = fminf(cand, 0.05f);
    dt_out[0] = isfinite(cand) ? cand : prev;
  }
}

// ---------------------------------------------------------------------------
// fp8 MX-MFMA GEMM — EXACT r6 version (best measured: 409.3us total).
// C = epi(A[M,K] @ Bt[N,K]^T)
// Block 128x64, 256 thr = 4 waves (2x2; wave-tile 64x32 = 4x2 of 16x16).
// MFMA = mfma_scale_f32_16x16x128_f8f6f4 with unit scales (e8m0 0x7F):
// bit-identical e4m3 products vs 16x16x32_fp8_fp8 at 2.2x per-inst FLOPs.
// VGPR-staged dbuf (48 KiB LDS, 2 blk/CU, 512 blocks = 2 waves/SIMD);
// global loads issued pre-MFMA, ds_writes post-MFMA, one barrier per K-tile.
// LDS: row-major [rows][128B], 16B slots XOR-swizzled slot^=(row&7) both
// sides -> conflict-free.
// Plateau evidence (r6-r10): gload_lds-drain, 2-deep counted vmcnt,
// XCD-swizzle(+FETCH -33%), setprio, 64x64-occupancy, 128x128-tile all
// neutral-to-regressive vs this config => binder is cross-XCD L2-miss
// latency on producer-consumer operands + serial leapfrog chain, not
// in-kernel schedule.
// EPI: 0 f32 partial (split-K) | 1 fp8 tanh(v/16+bias)
//      2 fp8 32*(1-t^2)*w3[col] | 3 fp8 (v/16)*(1-h^2)
// ---------------------------------------------------------------------------
template <int EPI>
__global__ __launch_bounds__(256, 2) void mfma_gemm8(
    const unsigned char* __restrict__ A, int lda,
    const unsigned char* __restrict__ Bt, int ldb,
    void* __restrict__ Cv, int ldc,
    const float* __restrict__ bias,
    const float* __restrict__ w3,
    const unsigned char* __restrict__ aux, int ldaux,
    int Kslice) {
  __shared__ __align__(16) unsigned char sA[2][128 * 128];
  __shared__ __align__(16) unsigned char sB[2][64 * 128];

  const int tid = threadIdx.x;
  const int lane = tid & 63;
  const int w = tid >> 6;
  const int wm = w & 1, wn = w >> 1;
  const int row0 = blockIdx.y * 128;
  const int col0 = blockIdx.x * 64;
  const int koff = blockIdx.z * Kslice;

  // staging: A 4 chunks (16B), B 2 chunks per thread per BK=128 tile
  const unsigned char* gA[4]; int wA[4];
  const unsigned char* gB[2]; int wB[2];
#pragma unroll
  for (int i = 0; i < 4; i++) {
    int c = i * 256 + tid;       // 0..1023
    int m = c >> 3, s = c & 7;   // row, 16B slot
    gA[i] = A + (size_t)(row0 + m) * lda + koff + s * 16;
    wA[i] = m * 128 + ((s ^ (m & 7)) << 4);
  }
#pragma unroll
  for (int i = 0; i < 2; i++) {
    int c = i * 256 + tid;       // 0..511
    int m = c >> 3, s = c & 7;
    gB[i] = Bt + (size_t)(col0 + m) * ldb + koff + s * 16;
    wB[i] = m * 128 + ((s ^ (m & 7)) << 4);
  }

  // fragment read offsets: lane needs k bytes [q*32, q*32+32) of its row
  // -> logical slots 2q, 2q+1, physically XOR'd by (row&7)
  const int q = lane >> 4, r = lane & 15;
  int aoff[4][2], boff[2][2];
#pragma unroll
  for (int i = 0; i < 4; i++) {
    int ma = wm * 64 + i * 16 + r;
#pragma unroll
    for (int H = 0; H < 2; H++)
      aoff[i][H] = ma * 128 + (((2 * q + H) ^ (ma & 7)) << 4);
  }
#pragma unroll
  for (int j = 0; j < 2; j++) {
    int mb = wn * 32 + j * 16 + r;
#pragma unroll
    for (int H = 0; H < 2; H++)
      boff[j][H] = mb * 128 + (((2 * q + H) ^ (mb & 7)) << 4);
  }

  f32x4 acc[4][2] = {};
  f32x4 rA[4], rB[2];

  // tile 0: global -> regs -> LDS buf0
#pragma unroll
  for (int i = 0; i < 4; i++) rA[i] = *(const f32x4*)gA[i];
#pragma unroll
  for (int i = 0; i < 2; i++) rB[i] = *(const f32x4*)gB[i];
#pragma unroll
  for (int i = 0; i < 4; i++) *(f32x4*)(&sA[0][0] + wA[i]) = rA[i];
#pragma unroll
  for (int i = 0; i < 2; i++) *(f32x4*)(&sB[0][0] + wB[i]) = rB[i];
  __syncthreads();

  int cur = 0;
  for (int k0 = 0; k0 < Kslice; k0 += 128) {
    const bool more = (k0 + 128 < Kslice);
    if (more) {  // next-tile loads: covered by the MFMA phase below
#pragma unroll
      for (int i = 0; i < 4; i++) rA[i] = *(const f32x4*)(gA[i] + k0 + 128);
#pragma unroll
      for (int i = 0; i < 2; i++) rB[i] = *(const f32x4*)(gB[i] + k0 + 128);
    }

    const unsigned char* bA = &sA[cur][0];
    const unsigned char* bB = &sB[cur][0];
    i32x8 af[4], bfr[2];
#pragma unroll
    for (int i = 0; i < 4; i++) {
      i32x4 lo = *(const i32x4*)(bA + aoff[i][0]);
      i32x4 hi = *(const i32x4*)(bA + aoff[i][1]);
      af[i] = __builtin_shufflevector(lo, hi, 0, 1, 2, 3, 4, 5, 6, 7);
    }
#pragma unroll
    for (int j = 0; j < 2; j++) {
      i32x4 lo = *(const i32x4*)(bB + boff[j][0]);
      i32x4 hi = *(const i32x4*)(bB + boff[j][1]);
      bfr[j] = __builtin_shufflevector(lo, hi, 0, 1, 2, 3, 4, 5, 6, 7);
    }
#pragma unroll
    for (int i = 0; i < 4; i++)
#pragma unroll
      for (int j = 0; j < 2; j++)
        acc[i][j] = __builtin_amdgcn_mfma_scale_f32_16x16x128_f8f6f4(
            af[i], bfr[j], acc[i][j], 0 /*fp8 A*/, 0 /*fp8 B*/,
            0, 0x7F7F7F7F, 0, 0x7F7F7F7F);  // unit scales

    if (more) {  // ds_write next tile (vmcnt wait lands here, post-MFMA)
      unsigned char* nA = &sA[cur ^ 1][0];
      unsigned char* nB = &sB[cur ^ 1][0];
#pragma unroll
      for (int i = 0; i < 4; i++) *(f32x4*)(nA + wA[i]) = rA[i];
#pragma unroll
      for (int i = 0; i < 2; i++) *(f32x4*)(nB + wB[i]) = rB[i];
    }
    __syncthreads();
    cur ^= 1;
  }

  // epilogue: C/D layout col=lane&15, row=(lane>>4)*4+reg
  float* Cf = (float*)Cv;
  unsigned char* C8 = (unsigned char*)Cv;
  float* Pz = Cf + (size_t)blockIdx.z * (size_t)gridDim.y * 128 * ldc;

#pragma unroll
  for (int i = 0; i < 4; i++) {
    int rowb = row0 + wm * 64 + i * 16 + q * 4;
#pragma unroll
    for (int j = 0; j < 2; j++) {
      int col = col0 + wn * 32 + j * 16 + r;
      if (EPI == 0) {
#pragma unroll
        for (int g = 0; g < 4; g++)
          Pz[(size_t)(rowb + g) * ldc + col] = acc[i][j][g];
      } else {
        float o[4];
#pragma unroll
        for (int g = 0; g < 4; g++) {
          float v = acc[i][j][g] * 0.0625f;  // undo weight x16
          if (EPI == 1) {
            o[g] = tanhf(v + bias[col]);
          } else if (EPI == 2) {
            float t = tanhf(v + bias[col]);
            o[g] = 32.f * (1.f - t * t) * w3[col];
          } else {
            float h = fp8_to_f32(aux[(size_t)(rowb + g) * ldaux + col]);
            o[g] = v * (1.f - h * h);
          }
        }
        int p = pack_fp8x4(o[0], o[1], o[2], o[3]);
#pragma unroll
        for (int g = 0; g < 4; g++)
          C8[(size_t)(rowb + g) * ldc + col] =
              (unsigned char)((p >> (8 * g)) & 0xff);
      }
    }
  }
}

// ---------------------------------------------------------------------------
// bf16 MFMA GEMM (W_out only, precision-critical): f32 split-K partials.
// ---------------------------------------------------------------------------
__global__ __launch_bounds__(256, 2) void mfma_gemm_bf16(
    const __bf16* __restrict__ A, int lda,
    const __bf16* __restrict__ Bt, int ldb,
    float* __restrict__ P, int ldc,
    int Kslice) {
  __shared__ __bf16 sA[2][128 * 64];
  __shared__ __bf16 sB[2][64 * 64];

  const int tid = threadIdx.x;
  const int lane = tid & 63;
  const int w = tid >> 6;
  const int wm = w & 1, wn = w >> 1;
  const int row0 = blockIdx.y * 128;
  const int col0 = blockIdx.x * 64;
  const int koff = blockIdx.z * Kslice;

  const __bf16* gA[4]; int lofA[4];
  const __bf16* gB[2]; int lofB[2];
#pragma unroll
  for (int i = 0; i < 4; i++) {
    int c = i * 256 + tid;
    int m = c >> 3, cc = c & 7;
    int o = cc ^ (m & 7);
    gA[i] = A + (size_t)(row0 + m) * lda + koff + o * 8;
    lofA[i] = c * 8;
  }
#pragma unroll
  for (int i = 0; i < 2; i++) {
    int c = i * 256 + tid;
    int m = c >> 3, cc = c & 7;
    int o = cc ^ (m & 7);
    gB[i] = Bt + (size_t)(col0 + m) * ldb + koff + o * 8;
    lofB[i] = c * 8;
  }

  const int q = lane >> 4, r = lane & 15;
  int aoff[4][2], boff[2][2];
#pragma unroll
  for (int i = 0; i < 4; i++) {
    int ma = wm * 64 + i * 16 + r;
#pragma unroll
    for (int h = 0; h < 2; h++)
      aoff[i][h] = (ma * 8 + ((h * 4 + q) ^ (ma & 7))) * 8;
  }
#pragma unroll
  for (int j = 0; j < 2; j++) {
    int mb = wn * 32 + j * 16 + r;
#pragma unroll
    for (int h = 0; h < 2; h++)
      boff[j][h] = (mb * 8 + ((h * 4 + q) ^ (mb & 7))) * 8;
  }

  f32x4 acc[4][2] = {};

#pragma unroll
  for (int i = 0; i < 4; i++) gload_lds16(gA[i], &sA[0][0] + lofA[i]);
#pragma unroll
  for (int i = 0; i < 2; i++) gload_lds16(gB[i], &sB[0][0] + lofB[i]);

  int cur = 0;
  for (int k0 = 0; k0 < Kslice; k0 += 64) {
    __syncthreads();
    if (k0 + 64 < Kslice) {
      int nxt = cur ^ 1;
#pragma unroll
      for (int i = 0; i < 4; i++)
        gload_lds16(gA[i] + k0 + 64, &sA[nxt][0] + lofA[i]);
#pragma unroll
      for (int i = 0; i < 2; i++)
        gload_lds16(gB[i] + k0 + 64, &sB[nxt][0] + lofB[i]);
    }
#pragma unroll
    for (int h = 0; h < 2; h++) {
      bf16x8 af[4], bfr[2];
#pragma unroll
      for (int i = 0; i < 4; i++)
        af[i] = *(const bf16x8*)(&sA[cur][0] + aoff[i][h]);
#pragma unroll
      for (int j = 0; j < 2; j++)
        bfr[j] = *(const bf16x8*)(&sB[cur][0] + boff[j][h]);
#pragma unroll
      for (int i = 0; i < 4; i++)
#pragma unroll
        for (int j = 0; j < 2; j++)
          acc[i][j] = __builtin_amdgcn_mfma_f32_16x16x32_bf16(af[i], bfr[j],
                                                              acc[i][j], 0, 0, 0);
    }
    cur ^= 1;
  }

  float* Pz = P + (size_t)blockIdx.z * (size_t)gridDim.y * 128 * ldc;
#pragma unroll
  for (int i = 0; i < 4; i++) {
    int rowb = row0 + wm * 64 + i * 16 + q * 4;
#pragma unroll
    for (int j = 0; j < 2; j++) {
      int col = col0 + wn * 32 + j * 16 + r;
#pragma unroll
      for (int g = 0; g < 4; g++)
        Pz[(size_t)(rowb + g) * ldc + col] = acc[i][j][g];
    }
  }
}

// ---------------------------------------------------------------------------
// grad = sum of 4 split-K partials (scaled 1/512 for fp8 scales);
// z[:, off:off+512] += coef*dt*grad ; refresh zb (bf16) and zf8 (fp8).
// If hout != nullptr (final q/p updates), also write into out_hnxt.
// ---------------------------------------------------------------------------
__global__ void update_kernel(float* __restrict__ z, __bf16* __restrict__ zb,
                              unsigned char* __restrict__ zf8,
                              const float* __restrict__ gp,
                              const float* __restrict__ dt,
                              float coef, int off,
                              float* __restrict__ hout) {
  int t = blockIdx.x * blockDim.x + threadIdx.x;  // 0 .. NB*SD/4
  int b = t >> 7;
  int j4 = t & 127;
  const f32x4* g4 = (const f32x4*)gp;
  constexpr int STRIDE = NB * SD / 4;
  f32x4 g = g4[t] + g4[t + STRIDE] + g4[t + 2 * STRIDE] + g4[t + 3 * STRIDE];
  int zi4 = (b * ZD + off) / 4 + j4;
  f32x4 v = ((f32x4*)z)[zi4];
  float s = coef * dt[0] * (1.f / 512.f);  // undo x16(w) * x32(g1)
  v[0] += s * g[0]; v[1] += s * g[1]; v[2] += s * g[2]; v[3] += s * g[3];
  ((f32x4*)z)[zi4] = v;
  bf16x4 o;
  o[0] = (__bf16)v[0]; o[1] = (__bf16)v[1];
  o[2] = (__bf16)v[2]; o[3] = (__bf16)v[3];
  ((bf16x4*)zb)[zi4] = o;
  ((int*)zf8)[zi4] = pack_fp8x4(v[0], v[1], v[2], v[3]);
  if (hout) {  // h_next row stride 2048 f32 = 512 f32x4; [q,p] = first 1024
    ((f32x4*)hout)[b * 512 + (off >> 2) + j4] = v;
  }
}

// ---------------------------------------------------------------------------
// W_out split-K=2 reduce + bias (f32, x4 vec)
// ---------------------------------------------------------------------------
__global__ void wout_reduce(const float* __restrict__ gp,
                            const float* __restrict__ b_out,
                            float* __restrict__ out) {
  int t = blockIdx.x * blockDim.x + threadIdx.x;  // 0 .. NB*1024/4
  constexpr int S = NB * 1024 / 4;
  const f32x4* g4 = (const f32x4*)gp;
  f32x4 v = g4[t] + g4[t + S];
  f32x4 bb = ((const f32x4*)b_out)[t & 255];
  v[0] += bb[0]; v[1] += bb[1]; v[2] += bb[2]; v[3] += bb[3];
  ((f32x4*)out)[t] = v;
}

// ---------------------------------------------------------------------------
extern "C" void kernel_launch(void* const* d_in, const int* in_sizes, int n_in,
                              void* d_out, int out_size, void* d_ws,
                              size_t ws_size, hipStream_t stream) {
  const float* x        = (const float*)d_in[0];
  const float* h_padded = (const float*)d_in[1];
  const float* W1    = (const float*)d_in[3];
  const float* b1    = (const float*)d_in[4];
  const float* W2    = (const float*)d_in[5];
  const float* b2    = (const float*)d_in[6];
  const float* W3    = (const float*)d_in[7];
  const float* W_out = (const float*)d_in[9];
  const float* b_out = (const float*)d_in[10];
  const float* enc_W = (const float*)d_in[11];
  const float* enc_b = (const float*)d_in[12];
  const float* thetas = (const float*)d_in[13];
  const float* gain   = (const float*)d_in[14];
  const float* shift  = (const float*)d_in[15];
  const float* cap_p  = (const float*)d_in[16];
  const float* t_bias = (const float*)d_in[17];
  const float* l_stab = (const float*)d_in[18];

  float* out_mat  = (float*)d_out;              // (2048,1024)
  float* out_hnxt = (float*)d_out + NB * 1024;  // (2048,16,128)

  // workspace layout (bytes)
  char* base = (char*)d_ws;
  float* z      = (float*)(base);                      // 16MB f32
  float* part   = (float*)(base + 16 * MB_);           // 16MB f32 partials
  __bf16* zb    = (__bf16*)(base + 32 * MB_);          // 8MB bf16
  __bf16* Wot   = (__bf16*)(base + 40 * MB_);          // 2MB bf16
  float* angl   = (float*)(base + 42 * MB_);           // 48KB
  float* dtp    = (float*)(base + 42 * MB_ + 65536);   // scalar
  float* simp   = (float*)(base + 42 * MB_ + 80 * 1024);  // 512 partials
  unsigned char* zf8  = (unsigned char*)(base + 43 * MB_);  // 4MB each:
  unsigned char* h1_8 = zf8 + (size_t)NELEM_Z;
  unsigned char* g2_8 = h1_8 + (size_t)NELEM_Z;
  unsigned char* g1_8 = g2_8 + (size_t)NELEM_Z;
  unsigned char* W1n8 = g1_8 + (size_t)NELEM_Z;
  unsigned char* W1t8 = W1n8 + (size_t)NELEM_Z;
  unsigned char* W2n8 = W1t8 + (size_t)NELEM_Z;
  unsigned char* W2t8 = W2n8 + (size_t)NELEM_Z;

  dim3 thr256(256);
  dim3 thrT(32, 8);

  // 1. weight prep: single launch (W1, W2 fp8 x16; W_out bf16^T)
  prep_all<<<dim3(64, 64, 3), thrT, 0, stream>>>(W1, W2, W_out, W1n8, W1t8,
                                                 W2n8, W2t8, Wot);

  // 2. build z (f32/bf16/fp8) + angles + h_next zero tail; then sim + dt
  build_z_kernel<<<dim3(NB), thr256, 0, stream>>>(x, h_padded, enc_W, enc_b, z,
                                                  zb, zf8, angl, out_hnxt);
  sim_kernel<<<dim3(NB / 4), thr256, 0, stream>>>(angl, thetas, gain, shift,
                                                  simp);
  dt_kernel<<<dim3(1), thr256, 0, stream>>>(simp, cap_p, t_bias, l_stab, dtp);

  // 3. three leapfrog gradient evaluations (all-fp8 MX grad path)
  const int   j0r[3]  = {0, 512, 0};
  const int   offs[3] = {512, 0, 512};
  const float coef[3] = {-0.5f, 1.0f, -0.5f};
  float* houts[3];
  houts[0] = nullptr;    // p_half: internal only
  houts[1] = out_hnxt;   // q_next -> h_next[:, 0:512]
  houts[2] = out_hnxt;   // p_next -> h_next[:, 512:1024]

  dim3 gridSq(32, 16, 1);   // 2048x2048, 128x64 tiles -> 512 blocks (2/CU)
  dim3 gridGr(8, 16, 4);    // 2048x512, split-K=4     -> 512 blocks

  for (int i = 0; i < 3; i++) {
    // h1 = tanh(z @ W1 + b1)                       (fp8 out)
    mfma_gemm8<1><<<gridSq, thr256, 0, stream>>>(
        zf8, ZD, W1t8, ZD, h1_8, ZD, b1, nullptr, nullptr, 0, ZD);
    // g2 = 32*(1 - tanh(h1 @ W2 + b2)^2) * W3[col] (fp8 out)
    mfma_gemm8<2><<<gridSq, thr256, 0, stream>>>(
        h1_8, ZD, W2t8, ZD, g2_8, ZD, b2, W3, nullptr, 0, ZD);
    // g1 = (g2 @ W2^T)/16 * (1 - h1^2)             (fp8 out, carries x32)
    mfma_gemm8<3><<<gridSq, thr256, 0, stream>>>(
        g2_8, ZD, W2n8, ZD, g1_8, ZD, nullptr, nullptr, h1_8, ZD, ZD);
    // part = g1 @ W1[j0:j0+512,:]^T  (f32 partials, split-K=4)
    mfma_gemm8<0><<<gridGr, thr256, 0, stream>>>(
        g1_8, ZD, W1n8 + (size_t)j0r[i] * ZD, ZD, part, SD, nullptr, nullptr,
        nullptr, 0, 512);
    // z[:, offs] += coef*dt*sum(part)/512  (+ h_next write on i=1,2)
    update_kernel<<<dim3(NB * SD / 4 / 256), thr256, 0, stream>>>(
        z, zb, zf8, part, dtp, coef[i], offs[i], houts[i]);
  }

  // 4. out = z[:, :1024] @ W_out + b_out  (bf16, split-K=2 + reduce)
  mfma_gemm_bf16<<<dim3(16, 16, 2), thr256, 0, stream>>>(zb, ZD, Wot, 1024,
                                                         part, 1024, 512);
  wout_reduce<<<dim3(NB * 1024 / 4 / 256), thr256, 0, stream>>>(part, b_out,
                                                                out_mat);
}